// Round 1
// baseline (12976.738 us; speedup 1.0000x reference)
//
#include <hip/hip_runtime.h>
#include <hip/hip_fp16.h>
#include <cstdint>

#define BB 32
#define TT 2048
#define DD 128
#define HH 256
#define KTOT 384   // D + H
#define NQ 12      // chunks of 8 halves per k-quarter (96 halves)

typedef _Float16 half2_t __attribute__((ext_vector_type(2)));

__device__ inline float dot2f16(uint32_t a, uint32_t b, float c) {
#if __has_builtin(__builtin_amdgcn_fdot2)
  half2_t ah = __builtin_bit_cast(half2_t, a);
  half2_t bh = __builtin_bit_cast(half2_t, b);
  return __builtin_amdgcn_fdot2(ah, bh, c, false);
#else
  float d;
  asm("v_dot2_f32_f16 %0, %1, %2, %3" : "=v"(d) : "v"(a), "v"(b), "v"(c));
  return d;
#endif
}

__device__ inline float fsigmoid(float x) { return __frcp_rn(1.f + __expf(-x)); }
__device__ inline float ftanh_(float x)   { return 1.f - 2.f * __frcp_rn(1.f + __expf(2.f * x)); }

// Repack [W;U] (384 x 1024 fp32, per-gate) into fp16 tiles:
// element (g, q, j, r): addr = ((g*12 + q)*1024 + j)*8 + r
// thread j = n*4 + s (n = hidden unit, s = k-quarter), k = s*96 + q*8 + r
__global__ void repack_kernel(const float* __restrict__ wf, const float* __restrict__ wi,
                              const float* __restrict__ wo, const float* __restrict__ wc,
                              const float* __restrict__ uf, const float* __restrict__ ui,
                              const float* __restrict__ uo, const float* __restrict__ uc,
                              __half* __restrict__ Vt) {
  int idx = blockIdx.x * 256 + threadIdx.x;      // 0 .. 393215
  int gq = idx >> 13;                            // (g*12 + q)
  int g = gq / 12;
  int q = gq - g * 12;
  int rem = idx & 8191;
  int j = rem >> 3;
  int r = rem & 7;
  int n = j >> 2;
  int s = j & 3;
  int k = s * 96 + q * 8 + r;
  const float* Wg[4] = {wf, wi, wo, wc};
  const float* Ug[4] = {uf, ui, uo, uc};
  float v = (k < DD) ? Wg[g][k * HH + n] : Ug[g][(k - DD) * HH + n];
  Vt[idx] = __float2half(v);
}

__global__ __launch_bounds__(1024, 4) void lstm_kernel(
    const float* __restrict__ x, const __half* __restrict__ Vt,
    const float* __restrict__ bf, const float* __restrict__ bi,
    const float* __restrict__ bo, const float* __restrict__ bc,
    float* __restrict__ out) {
  __shared__ __align__(16) __half hx[2][KTOT];   // [x_t(128) ; h(256)] as fp16, double-buffered
  const int j = threadIdx.x;
  const int b = blockIdx.x;
  const int n = j >> 2;
  const int s = j & 3;

  const float* xb = x + (size_t)b * TT * DD;
  float* ob = out + (size_t)b * TT * HH;

  const float bias_f = bf[n];
  const float bias_i = bi[n];
  const float bias_o = bo[n];
  const float bias_c = bc[n];

  // init: h = 0, load x[t=0]
  if (j < HH) hx[0][DD + j] = __float2half(0.f);
  if (j < 32) {
    float4 xa = ((const float4*)xb)[j];
    __half2* dst = (__half2*)hx[0];
    __half2 p0; p0.x = __float2half(xa.x); p0.y = __float2half(xa.y);
    __half2 p1; p1.x = __float2half(xa.z); p1.y = __float2half(xa.w);
    dst[2 * j] = p0; dst[2 * j + 1] = p1;
  }

  float c = 0.f;
  const uint4* vbase = (const uint4*)Vt + j;   // element ((g*12+q)*1024 + j)

  int cur = 0;
  for (int t = 0; t < TT; ++t) {
    const int nxt = cur ^ 1;
    __syncthreads();   // hx[cur] fully written (prologue or previous iteration)

    // prefetch x[t+1] into the other buffer while everyone computes on hx[cur]
    if (j < 32 && t + 1 < TT) {
      float4 xa = ((const float4*)(xb + (size_t)(t + 1) * DD))[j];
      __half2* dst = (__half2*)hx[nxt];
      __half2 p0; p0.x = __float2half(xa.x); p0.y = __float2half(xa.y);
      __half2 p1; p1.x = __float2half(xa.z); p1.y = __float2half(xa.w);
      dst[2 * j] = p0; dst[2 * j + 1] = p1;
    }

    float af = 0.f, ai = 0.f, ao = 0.f, ac = 0.f;
    const uint4* hp = (const uint4*)(&hx[cur][s * 96]);
#pragma unroll 4
    for (int q = 0; q < NQ; ++q) {
      uint4 hq = hp[q];
      uint4 v0 = vbase[(0 * NQ + q) * 1024];
      uint4 v1 = vbase[(1 * NQ + q) * 1024];
      uint4 v2 = vbase[(2 * NQ + q) * 1024];
      uint4 v3 = vbase[(3 * NQ + q) * 1024];
      af = dot2f16(v0.x, hq.x, af); af = dot2f16(v0.y, hq.y, af);
      af = dot2f16(v0.z, hq.z, af); af = dot2f16(v0.w, hq.w, af);
      ai = dot2f16(v1.x, hq.x, ai); ai = dot2f16(v1.y, hq.y, ai);
      ai = dot2f16(v1.z, hq.z, ai); ai = dot2f16(v1.w, hq.w, ai);
      ao = dot2f16(v2.x, hq.x, ao); ao = dot2f16(v2.y, hq.y, ao);
      ao = dot2f16(v2.z, hq.z, ao); ao = dot2f16(v2.w, hq.w, ao);
      ac = dot2f16(v3.x, hq.x, ac); ac = dot2f16(v3.y, hq.y, ac);
      ac = dot2f16(v3.z, hq.z, ac); ac = dot2f16(v3.w, hq.w, ac);
    }

    // reduce the 4 k-quarters within each lane-quad (all 4 lanes end with full sums)
    af += __shfl_xor(af, 1); af += __shfl_xor(af, 2);
    ai += __shfl_xor(ai, 1); ai += __shfl_xor(ai, 2);
    ao += __shfl_xor(ao, 1); ao += __shfl_xor(ao, 2);
    ac += __shfl_xor(ac, 1); ac += __shfl_xor(ac, 2);

    float fg = fsigmoid(af + bias_f);
    float ig = fsigmoid(ai + bias_i);
    float og = fsigmoid(ao + bias_o);
    float cd = ftanh_(ac + bias_c);
    c = fg * c + ig * cd;
    float hv = og * ftanh_(c);

    if (s == 0) {
      hx[nxt][DD + n] = __float2half(hv);
      ob[(size_t)t * HH + n] = hv;
    }
    cur = nxt;
  }
}

extern "C" void kernel_launch(void* const* d_in, const int* in_sizes, int n_in,
                              void* d_out, int out_size, void* d_ws, size_t ws_size,
                              hipStream_t stream) {
  const float* x  = (const float*)d_in[0];
  const float* wf = (const float*)d_in[1];
  const float* wi = (const float*)d_in[2];
  const float* wo = (const float*)d_in[3];
  const float* wc = (const float*)d_in[4];
  const float* uf = (const float*)d_in[5];
  const float* ui = (const float*)d_in[6];
  const float* uo = (const float*)d_in[7];
  const float* uc = (const float*)d_in[8];
  const float* bf = (const float*)d_in[9];
  const float* bi = (const float*)d_in[10];
  const float* bo = (const float*)d_in[11];
  const float* bc = (const float*)d_in[12];

  __half* Vt = (__half*)d_ws;   // 4*12*1024*8 halves = 768 KB

  repack_kernel<<<1536, 256, 0, stream>>>(wf, wi, wo, wc, uf, ui, uo, uc, Vt);
  lstm_kernel<<<32, 1024, 0, stream>>>(x, Vt, bf, bi, bo, bc, (float*)d_out);
}

// Round 2
// 9257.959 us; speedup vs baseline: 1.4017x; 1.4017x over previous
//
#include <hip/hip_runtime.h>
#include <hip/hip_fp16.h>
#include <cstdint>

#define BB 32
#define TT 2048
#define DD 128
#define HH 256

typedef _Float16 half2v __attribute__((ext_vector_type(2)));

__device__ inline float dot2f16(uint32_t a, uint32_t b, float c) {
#if __has_builtin(__builtin_amdgcn_fdot2)
  half2v ah = __builtin_bit_cast(half2v, a);
  half2v bh = __builtin_bit_cast(half2v, b);
  return __builtin_amdgcn_fdot2(ah, bh, c, false);
#else
  float d;
  asm("v_dot2_f32_f16 %0, %1, %2, %3" : "=v"(d) : "v"(a), "v"(b), "v"(c));
  return d;
#endif
}

__device__ inline float fsigmoid(float x) { return __frcp_rn(1.f + __expf(-x)); }
__device__ inline float ftanh_(float x)   { return 1.f - 2.f * __frcp_rn(1.f + __expf(2.f * x)); }

// ---------------------------------------------------------------------------
// Fast path (needs ~129 MB ws): precomputed xg + pipelined recurrent kernel
// ---------------------------------------------------------------------------

// Ut[((g*8+q)*1024 + j)*8 + r] = U_g[k][n], k = (j&3)*64 + q*8 + r, n = j>>2
__global__ void repack_u2_kernel(const float* __restrict__ uf, const float* __restrict__ ui_,
                                 const float* __restrict__ uo, const float* __restrict__ uc,
                                 __half* __restrict__ Ut) {
  int idx = blockIdx.x * 256 + threadIdx.x;   // < 262144
  int gq = idx >> 13;
  int g = gq >> 3, q = gq & 7;
  int rem = idx & 8191;
  int jj = rem >> 3, r = rem & 7;
  int s = jj & 3, n = jj >> 2;
  int k = s * 64 + q * 8 + r;
  const float* U[4] = {uf, ui_, uo, uc};
  Ut[idx] = __float2half(U[g][k * HH + n]);
}

// Wt[m*128 + k] = W_g[k][n], m = n*4+g;  bs[m] = b_g[n]
__global__ void repack_w2_kernel(const float* __restrict__ wf, const float* __restrict__ wi,
                                 const float* __restrict__ wo, const float* __restrict__ wc,
                                 const float* __restrict__ bf, const float* __restrict__ bi,
                                 const float* __restrict__ bo, const float* __restrict__ bc,
                                 __half* __restrict__ Wt, float* __restrict__ bs) {
  int idx = blockIdx.x * 256 + threadIdx.x;   // < 131072
  int m = idx >> 7, k = idx & 127;
  int g = m & 3, n = m >> 2;
  const float* W[4] = {wf, wi, wo, wc};
  Wt[idx] = __float2half(W[g][k * HH + n]);
  if (idx < 1024) {
    const float* B[4] = {bf, bi, bo, bc};
    bs[idx] = B[idx & 3][idx >> 2];
  }
}

// xg[row][m] = sum_k x[row][k] * Wt[m][k] + bs[m]   (row = b*T+t, m = n*4+g)
__global__ __launch_bounds__(256, 4) void xg_gemm_kernel(
    const float* __restrict__ x, const __half* __restrict__ Wt,
    const float* __restrict__ bs, __half* __restrict__ xg) {
  __shared__ __align__(16) __half As[64][136];
  __shared__ __align__(16) __half Bs[64][136];
  const int tid = threadIdx.x;
  const int r0 = (blockIdx.x >> 4) * 64;
  const int m0 = (blockIdx.x & 15) * 64;

#pragma unroll
  for (int it = 0; it < 8; ++it) {
    int fi = it * 256 + tid;
    int row = fi >> 5, col4 = fi & 31;
    float4 v = ((const float4*)(x + (size_t)(r0 + row) * DD))[col4];
    __half2 lo; lo.x = __float2half(v.x); lo.y = __float2half(v.y);
    __half2 hi; hi.x = __float2half(v.z); hi.y = __float2half(v.w);
    uint2 pk; pk.x = __builtin_bit_cast(uint32_t, lo); pk.y = __builtin_bit_cast(uint32_t, hi);
    *(uint2*)&As[row][col4 * 4] = pk;
  }
#pragma unroll
  for (int it = 0; it < 4; ++it) {
    int ui = it * 256 + tid;
    int row = ui >> 4, c16 = ui & 15;
    uint4 v = ((const uint4*)(Wt + (size_t)(m0 + row) * DD))[c16];
    *(uint4*)&Bs[row][c16 * 8] = v;
  }
  __syncthreads();

  const int ty = tid >> 4, tx = tid & 15;
  float acc[4][4] = {};
#pragma unroll
  for (int kc = 0; kc < 16; ++kc) {
    uint4 av[4], bv[4];
#pragma unroll
    for (int d = 0; d < 4; ++d) {
      av[d] = *(const uint4*)&As[ty * 4 + d][kc * 8];
      bv[d] = *(const uint4*)&Bs[tx * 4 + d][kc * 8];
    }
#pragma unroll
    for (int di = 0; di < 4; ++di)
#pragma unroll
      for (int dj = 0; dj < 4; ++dj) {
        acc[di][dj] = dot2f16(av[di].x, bv[dj].x, acc[di][dj]);
        acc[di][dj] = dot2f16(av[di].y, bv[dj].y, acc[di][dj]);
        acc[di][dj] = dot2f16(av[di].z, bv[dj].z, acc[di][dj]);
        acc[di][dj] = dot2f16(av[di].w, bv[dj].w, acc[di][dj]);
      }
  }

#pragma unroll
  for (int di = 0; di < 4; ++di) {
    const int grow = r0 + ty * 4 + di;
    __half2 o01, o23;
    o01.x = __float2half(acc[di][0] + bs[m0 + tx * 4 + 0]);
    o01.y = __float2half(acc[di][1] + bs[m0 + tx * 4 + 1]);
    o23.x = __float2half(acc[di][2] + bs[m0 + tx * 4 + 2]);
    o23.y = __float2half(acc[di][3] + bs[m0 + tx * 4 + 3]);
    uint2 pk; pk.x = __builtin_bit_cast(uint32_t, o01); pk.y = __builtin_bit_cast(uint32_t, o23);
    *(uint2*)&xg[(size_t)grow * 1024 + m0 + tx * 4] = pk;
  }
}

__device__ inline void dotq(const uint4* P, const uint4& hq,
                            float& a0, float& a1, float& a2, float& a3) {
  a0 = dot2f16(P[0].x, hq.x, a0); a0 = dot2f16(P[0].y, hq.y, a0);
  a0 = dot2f16(P[0].z, hq.z, a0); a0 = dot2f16(P[0].w, hq.w, a0);
  a1 = dot2f16(P[1].x, hq.x, a1); a1 = dot2f16(P[1].y, hq.y, a1);
  a1 = dot2f16(P[1].z, hq.z, a1); a1 = dot2f16(P[1].w, hq.w, a1);
  a2 = dot2f16(P[2].x, hq.x, a2); a2 = dot2f16(P[2].y, hq.y, a2);
  a2 = dot2f16(P[2].z, hq.z, a2); a2 = dot2f16(P[2].w, hq.w, a2);
  a3 = dot2f16(P[3].x, hq.x, a3); a3 = dot2f16(P[3].y, hq.y, a3);
  a3 = dot2f16(P[3].z, hq.z, a3); a3 = dot2f16(P[3].w, hq.w, a3);
}

#define LD(g, q) (*(const uint4*)(Ut + (size_t)((g) * 8 + (q)) * 8192 + (size_t)j * 8))

__global__ __launch_bounds__(1024, 4) void lstm2_kernel(
    const __half* __restrict__ Ut, const __half* __restrict__ xg,
    float* __restrict__ out) {
  // h in LDS, chunked [s][64] with pad 16 halves -> bank-conflict-free ds_read_b128
  __shared__ __align__(16) __half hl[2][4][80];
  const int j = threadIdx.x;
  const int b = blockIdx.x;
  const int n = j >> 2, s = j & 3;
  const __half* xgb = xg + (size_t)b * TT * 1024;
  float* ob = out + (size_t)b * TT * HH;

  if (j < HH) hl[0][j >> 6][j & 63] = __float2half(0.f);

  // persistent groups q0,q1 (reloaded each step right after use -> latency
  // hidden across the whole step); stream slots S0..S2 cover q2..q7
  uint4 p0[4], p1[4], S0[4], S1[4], S2[4];
#pragma unroll
  for (int g = 0; g < 4; ++g) { p0[g] = LD(g, 0); p1[g] = LD(g, 1); }

  uint2 xgc = *(const uint2*)(xgb + (size_t)n * 4);
  float c = 0.f;
  int cur = 0;

  for (int t = 0; t < TT; ++t) {
    const int nxt = cur ^ 1;
    // issue stream loads early (constant data -> no dependence on h/barrier)
#pragma unroll
    for (int g = 0; g < 4; ++g) { S0[g] = LD(g, 2); S1[g] = LD(g, 3); S2[g] = LD(g, 4); }
    const int tn = (t + 1 < TT) ? (t + 1) : t;
    const uint2 xgn = *(const uint2*)(xgb + (size_t)tn * 1024 + (size_t)n * 4);

    // raw barrier: drain only LDS (h write), keep global loads in flight
    asm volatile("s_waitcnt lgkmcnt(0)" ::: "memory");
    __builtin_amdgcn_s_barrier();

    const __half* hrow = &hl[cur][s][0];
    float a0 = 0.f, a1 = 0.f, a2 = 0.f, a3 = 0.f;
    uint4 hq;

    hq = *(const uint4*)(hrow + 0);
    dotq(p0, hq, a0, a1, a2, a3);
#pragma unroll
    for (int g = 0; g < 4; ++g) p0[g] = LD(g, 0);   // for next step
    hq = *(const uint4*)(hrow + 8);
    dotq(p1, hq, a0, a1, a2, a3);
#pragma unroll
    for (int g = 0; g < 4; ++g) p1[g] = LD(g, 1);   // for next step
    hq = *(const uint4*)(hrow + 16);
    dotq(S0, hq, a0, a1, a2, a3);
#pragma unroll
    for (int g = 0; g < 4; ++g) S0[g] = LD(g, 5);
    hq = *(const uint4*)(hrow + 24);
    dotq(S1, hq, a0, a1, a2, a3);
#pragma unroll
    for (int g = 0; g < 4; ++g) S1[g] = LD(g, 6);
    hq = *(const uint4*)(hrow + 32);
    dotq(S2, hq, a0, a1, a2, a3);
#pragma unroll
    for (int g = 0; g < 4; ++g) S2[g] = LD(g, 7);
    hq = *(const uint4*)(hrow + 40);
    dotq(S0, hq, a0, a1, a2, a3);
    hq = *(const uint4*)(hrow + 48);
    dotq(S1, hq, a0, a1, a2, a3);
    hq = *(const uint4*)(hrow + 56);
    dotq(S2, hq, a0, a1, a2, a3);

    // quad reduction over k-quarters (DPP-lowered shfl_xor)
    a0 += __shfl_xor(a0, 1); a0 += __shfl_xor(a0, 2);
    a1 += __shfl_xor(a1, 1); a1 += __shfl_xor(a1, 2);
    a2 += __shfl_xor(a2, 1); a2 += __shfl_xor(a2, 2);
    a3 += __shfl_xor(a3, 1); a3 += __shfl_xor(a3, 2);

    const __half2 x01 = __builtin_bit_cast(__half2, xgc.x);
    const __half2 x23 = __builtin_bit_cast(__half2, xgc.y);
    const float gf = fsigmoid(a0 + __half2float(x01.x));
    const float gi = fsigmoid(a1 + __half2float(x01.y));
    const float go = fsigmoid(a2 + __half2float(x23.x));
    const float cd = ftanh_(a3 + __half2float(x23.y));
    c = gf * c + gi * cd;
    const float hv = go * ftanh_(c);
    if (s == 0) {
      hl[nxt][n >> 6][n & 63] = __float2half(hv);
      ob[(size_t)t * HH + n] = hv;
    }
    xgc = xgn;
    cur = nxt;
  }
}

// ---------------------------------------------------------------------------
// Fallback path (round-1 kernel, needs only 768 KB ws)
// ---------------------------------------------------------------------------

__global__ void repack_kernel(const float* __restrict__ wf, const float* __restrict__ wi,
                              const float* __restrict__ wo, const float* __restrict__ wc,
                              const float* __restrict__ uf, const float* __restrict__ ui,
                              const float* __restrict__ uo, const float* __restrict__ uc,
                              __half* __restrict__ Vt) {
  int idx = blockIdx.x * 256 + threadIdx.x;
  int gq = idx >> 13;
  int g = gq / 12;
  int q = gq - g * 12;
  int rem = idx & 8191;
  int jj = rem >> 3;
  int r = rem & 7;
  int n = jj >> 2;
  int s = jj & 3;
  int k = s * 96 + q * 8 + r;
  const float* Wg[4] = {wf, wi, wo, wc};
  const float* Ug[4] = {uf, ui, uo, uc};
  float v = (k < DD) ? Wg[g][k * HH + n] : Ug[g][(k - DD) * HH + n];
  Vt[idx] = __float2half(v);
}

__global__ __launch_bounds__(1024, 4) void lstm_kernel(
    const float* __restrict__ x, const __half* __restrict__ Vt,
    const float* __restrict__ bf, const float* __restrict__ bi,
    const float* __restrict__ bo, const float* __restrict__ bc,
    float* __restrict__ out) {
  __shared__ __align__(16) __half hx[2][384];
  const int j = threadIdx.x;
  const int b = blockIdx.x;
  const int n = j >> 2;
  const int s = j & 3;
  const float* xb = x + (size_t)b * TT * DD;
  float* ob = out + (size_t)b * TT * HH;
  const float bias_f = bf[n], bias_i = bi[n], bias_o = bo[n], bias_c = bc[n];

  if (j < HH) hx[0][DD + j] = __float2half(0.f);
  if (j < 32) {
    float4 xa = ((const float4*)xb)[j];
    __half2* dst = (__half2*)hx[0];
    __half2 p0q; p0q.x = __float2half(xa.x); p0q.y = __float2half(xa.y);
    __half2 p1q; p1q.x = __float2half(xa.z); p1q.y = __float2half(xa.w);
    dst[2 * j] = p0q; dst[2 * j + 1] = p1q;
  }
  float c = 0.f;
  const uint4* vbase = (const uint4*)Vt + j;
  int cur = 0;
  for (int t = 0; t < TT; ++t) {
    const int nxt = cur ^ 1;
    __syncthreads();
    if (j < 32 && t + 1 < TT) {
      float4 xa = ((const float4*)(xb + (size_t)(t + 1) * DD))[j];
      __half2* dst = (__half2*)hx[nxt];
      __half2 p0q; p0q.x = __float2half(xa.x); p0q.y = __float2half(xa.y);
      __half2 p1q; p1q.x = __float2half(xa.z); p1q.y = __float2half(xa.w);
      dst[2 * j] = p0q; dst[2 * j + 1] = p1q;
    }
    float af = 0.f, ai = 0.f, ao = 0.f, ac = 0.f;
    const uint4* hp = (const uint4*)(&hx[cur][s * 96]);
#pragma unroll 4
    for (int q = 0; q < 12; ++q) {
      uint4 hq = hp[q];
      uint4 v0 = vbase[(0 * 12 + q) * 1024];
      uint4 v1 = vbase[(1 * 12 + q) * 1024];
      uint4 v2 = vbase[(2 * 12 + q) * 1024];
      uint4 v3 = vbase[(3 * 12 + q) * 1024];
      af = dot2f16(v0.x, hq.x, af); af = dot2f16(v0.y, hq.y, af);
      af = dot2f16(v0.z, hq.z, af); af = dot2f16(v0.w, hq.w, af);
      ai = dot2f16(v1.x, hq.x, ai); ai = dot2f16(v1.y, hq.y, ai);
      ai = dot2f16(v1.z, hq.z, ai); ai = dot2f16(v1.w, hq.w, ai);
      ao = dot2f16(v2.x, hq.x, ao); ao = dot2f16(v2.y, hq.y, ao);
      ao = dot2f16(v2.z, hq.z, ao); ao = dot2f16(v2.w, hq.w, ao);
      ac = dot2f16(v3.x, hq.x, ac); ac = dot2f16(v3.y, hq.y, ac);
      ac = dot2f16(v3.z, hq.z, ac); ac = dot2f16(v3.w, hq.w, ac);
    }
    af += __shfl_xor(af, 1); af += __shfl_xor(af, 2);
    ai += __shfl_xor(ai, 1); ai += __shfl_xor(ai, 2);
    ao += __shfl_xor(ao, 1); ao += __shfl_xor(ao, 2);
    ac += __shfl_xor(ac, 1); ac += __shfl_xor(ac, 2);
    float fg = fsigmoid(af + bias_f);
    float ig = fsigmoid(ai + bias_i);
    float og = fsigmoid(ao + bias_o);
    float cd = ftanh_(ac + bias_c);
    c = fg * c + ig * cd;
    float hv = og * ftanh_(c);
    if (s == 0) {
      hx[nxt][DD + n] = __float2half(hv);
      ob[(size_t)t * HH + n] = hv;
    }
    cur = nxt;
  }
}

// ---------------------------------------------------------------------------

extern "C" void kernel_launch(void* const* d_in, const int* in_sizes, int n_in,
                              void* d_out, int out_size, void* d_ws, size_t ws_size,
                              hipStream_t stream) {
  const float* x  = (const float*)d_in[0];
  const float* wf = (const float*)d_in[1];
  const float* wi = (const float*)d_in[2];
  const float* wo = (const float*)d_in[3];
  const float* wc = (const float*)d_in[4];
  const float* uf = (const float*)d_in[5];
  const float* ui = (const float*)d_in[6];
  const float* uo = (const float*)d_in[7];
  const float* uc = (const float*)d_in[8];
  const float* bf = (const float*)d_in[9];
  const float* bi = (const float*)d_in[10];
  const float* bo = (const float*)d_in[11];
  const float* bc = (const float*)d_in[12];

  const size_t UT_OFF = 0;                       // 524288 B
  const size_t WT_OFF = 524288;                  // 262144 B
  const size_t BS_OFF = 786432;                  // 4096 B
  const size_t XG_OFF = 790528;                  // 134217728 B
  const size_t NEED = XG_OFF + (size_t)BB * TT * 1024 * 2;

  if (ws_size >= NEED) {
    __half* Ut = (__half*)((char*)d_ws + UT_OFF);
    __half* Wt = (__half*)((char*)d_ws + WT_OFF);
    float*  bs = (float*)((char*)d_ws + BS_OFF);
    __half* xg = (__half*)((char*)d_ws + XG_OFF);

    repack_u2_kernel<<<1024, 256, 0, stream>>>(uf, ui, uo, uc, Ut);
    repack_w2_kernel<<<512, 256, 0, stream>>>(wf, wi, wo, wc, bf, bi, bo, bc, Wt, bs);
    xg_gemm_kernel<<<16384, 256, 0, stream>>>(x, Wt, bs, xg);
    lstm2_kernel<<<BB, 1024, 0, stream>>>(Ut, xg, (float*)d_out);
  } else {
    __half* Vt = (__half*)d_ws;
    repack_kernel<<<1536, 256, 0, stream>>>(wf, wi, wo, wc, uf, ui, uo, uc, Vt);
    lstm_kernel<<<BB, 1024, 0, stream>>>(x, Vt, bf, bi, bo, bc, (float*)d_out);
  }
}

// Round 3
// 4089.034 us; speedup vs baseline: 3.1735x; 2.2641x over previous
//
#include <hip/hip_runtime.h>
#include <hip/hip_fp16.h>
#include <cstdint>

#define BB 32
#define TT 2048
#define DD 128
#define HH 256

typedef _Float16 half2v __attribute__((ext_vector_type(2)));

__device__ inline float dot2f16(uint32_t a, uint32_t b, float c) {
#if __has_builtin(__builtin_amdgcn_fdot2)
  half2v ah = __builtin_bit_cast(half2v, a);
  half2v bh = __builtin_bit_cast(half2v, b);
  return __builtin_amdgcn_fdot2(ah, bh, c, false);
#else
  float d;
  asm("v_dot2_f32_f16 %0, %1, %2, %3" : "=v"(d) : "v"(a), "v"(b), "v"(c));
  return d;
#endif
}

__device__ inline float fsigmoid(float x) { return __frcp_rn(1.f + __expf(-x)); }
__device__ inline float ftanh_(float x)   { return 1.f - 2.f * __frcp_rn(1.f + __expf(2.f * x)); }

// ---------------------------------------------------------------------------
// Fast path: precomputed xg + U fully on-chip (registers + LDS self-spill)
// ---------------------------------------------------------------------------

// Ut3[(cg*512 + j)*8 + r], cg = a*8 + c, a = nn*4 + g  (nn in {0,1}, g in {0..3})
// thread j: s = j&3 (k-quarter), u = j>>2; n = 2u+nn; k = s*64 + c*8 + r
__global__ void repack_u3_kernel(const float* __restrict__ uf, const float* __restrict__ ui_,
                                 const float* __restrict__ uo, const float* __restrict__ uc,
                                 __half* __restrict__ Ut) {
  int idx = blockIdx.x * 256 + threadIdx.x;   // < 262144
  int cg = idx >> 12;
  int rem = idx & 4095;
  int j = rem >> 3, r = rem & 7;
  int a = cg >> 3, c = cg & 7;
  int nn = a >> 2, g = a & 3;
  int s = j & 3, u = j >> 2;
  int n = 2 * u + nn;
  int k = s * 64 + c * 8 + r;
  const float* U[4] = {uf, ui_, uo, uc};
  Ut[idx] = __float2half(U[g][k * HH + n]);
}

// Wt[m*128 + k] = W_g[k][n], m = n*4+g;  bs[m] = b_g[n]
__global__ void repack_w2_kernel(const float* __restrict__ wf, const float* __restrict__ wi,
                                 const float* __restrict__ wo, const float* __restrict__ wc,
                                 const float* __restrict__ bf, const float* __restrict__ bi,
                                 const float* __restrict__ bo, const float* __restrict__ bc,
                                 __half* __restrict__ Wt, float* __restrict__ bs) {
  int idx = blockIdx.x * 256 + threadIdx.x;   // < 131072
  int m = idx >> 7, k = idx & 127;
  int g = m & 3, n = m >> 2;
  const float* W[4] = {wf, wi, wo, wc};
  Wt[idx] = __float2half(W[g][k * HH + n]);
  if (idx < 1024) {
    const float* B[4] = {bf, bi, bo, bc};
    bs[idx] = B[idx & 3][idx >> 2];
  }
}

// xg[row][m] = sum_k x[row][k] * Wt[m][k] + bs[m]   (row = b*T+t, m = n*4+g)
__global__ __launch_bounds__(256, 4) void xg_gemm_kernel(
    const float* __restrict__ x, const __half* __restrict__ Wt,
    const float* __restrict__ bs, __half* __restrict__ xg) {
  __shared__ __align__(16) __half As[64][136];
  __shared__ __align__(16) __half Bs[64][136];
  const int tid = threadIdx.x;
  const int r0 = (blockIdx.x >> 4) * 64;
  const int m0 = (blockIdx.x & 15) * 64;

#pragma unroll
  for (int it = 0; it < 8; ++it) {
    int fi = it * 256 + tid;
    int row = fi >> 5, col4 = fi & 31;
    float4 v = ((const float4*)(x + (size_t)(r0 + row) * DD))[col4];
    __half2 lo; lo.x = __float2half(v.x); lo.y = __float2half(v.y);
    __half2 hi; hi.x = __float2half(v.z); hi.y = __float2half(v.w);
    uint2 pk; pk.x = __builtin_bit_cast(uint32_t, lo); pk.y = __builtin_bit_cast(uint32_t, hi);
    *(uint2*)&As[row][col4 * 4] = pk;
  }
#pragma unroll
  for (int it = 0; it < 4; ++it) {
    int ui = it * 256 + tid;
    int row = ui >> 4, c16 = ui & 15;
    uint4 v = ((const uint4*)(Wt + (size_t)(m0 + row) * DD))[c16];
    *(uint4*)&Bs[row][c16 * 8] = v;
  }
  __syncthreads();

  const int ty = tid >> 4, tx = tid & 15;
  float acc[4][4] = {};
#pragma unroll
  for (int kc = 0; kc < 16; ++kc) {
    uint4 av[4], bv[4];
#pragma unroll
    for (int d = 0; d < 4; ++d) {
      av[d] = *(const uint4*)&As[ty * 4 + d][kc * 8];
      bv[d] = *(const uint4*)&Bs[tx * 4 + d][kc * 8];
    }
#pragma unroll
    for (int di = 0; di < 4; ++di)
#pragma unroll
      for (int dj = 0; dj < 4; ++dj) {
        acc[di][dj] = dot2f16(av[di].x, bv[dj].x, acc[di][dj]);
        acc[di][dj] = dot2f16(av[di].y, bv[dj].y, acc[di][dj]);
        acc[di][dj] = dot2f16(av[di].z, bv[dj].z, acc[di][dj]);
        acc[di][dj] = dot2f16(av[di].w, bv[dj].w, acc[di][dj]);
      }
  }

#pragma unroll
  for (int di = 0; di < 4; ++di) {
    const int grow = r0 + ty * 4 + di;
    __half2 o01, o23;
    o01.x = __float2half(acc[di][0] + bs[m0 + tx * 4 + 0]);
    o01.y = __float2half(acc[di][1] + bs[m0 + tx * 4 + 1]);
    o23.x = __float2half(acc[di][2] + bs[m0 + tx * 4 + 2]);
    o23.y = __float2half(acc[di][3] + bs[m0 + tx * 4 + 3]);
    uint2 pk; pk.x = __builtin_bit_cast(uint32_t, o01); pk.y = __builtin_bit_cast(uint32_t, o23);
    *(uint2*)&xg[(size_t)grow * 1024 + m0 + tx * 4] = pk;
  }
}

// Recurrent kernel: 512 threads (8 waves, 2/SIMD, VGPR cap 256).
// U resident on-chip: 48 uint4/thread in VGPRs (c=0..5) + 16 uint4/thread in
// LDS (c=6,7; per-thread self-spill, conflict-free).
__global__ __launch_bounds__(512, 2) void lstm3_kernel(
    const __half* __restrict__ Ut, const __half* __restrict__ xg,
    float* __restrict__ out) {
  __shared__ __align__(16) __half Ul[16 * 512 * 8];   // 128 KB
  __shared__ __align__(16) __half hl[2][HH];          // 1 KB

  const int j = threadIdx.x;
  const int b = blockIdx.x;
  const int s = j & 3, u = j >> 2;
  const int nsel = 2 * u + (s & 1);

  const __half* xgb = xg + (size_t)b * TT * 1024;
  float* ob = out + (size_t)b * TT * HH;

  // stage LDS-resident U chunks (c = 6,7): slot sl = a*2 + (c-6)
#pragma unroll
  for (int a = 0; a < 8; ++a)
#pragma unroll
    for (int c6 = 0; c6 < 2; ++c6) {
      uint4 v = *(const uint4*)(Ut + ((size_t)(a * 8 + 6 + c6) * 512 + j) * 8);
      *(uint4*)(Ul + ((size_t)(a * 2 + c6) * 512 + j) * 8) = v;
    }

  // register-resident U chunks (c = 0..5)
  uint4 R[48];
#pragma unroll
  for (int a = 0; a < 8; ++a)
#pragma unroll
    for (int c = 0; c < 6; ++c)
      R[a * 6 + c] = *(const uint4*)(Ut + ((size_t)(a * 8 + c) * 512 + j) * 8);

  if (j < HH) hl[0][j] = __float2half(0.f);

  uint2 xgc = *(const uint2*)(xgb + (size_t)nsel * 4);
  float cst = 0.f;
  int cur = 0;

  for (int t = 0; t < TT; ++t) {
    const int nxt = cur ^ 1;
    const int tn = (t + 1 < TT) ? (t + 1) : t;
    const uint2 xgn = *(const uint2*)(xgb + (size_t)tn * 1024 + (size_t)nsel * 4);

    // drain LDS (h write of prev step + staging), keep global loads in flight
    asm volatile("s_waitcnt lgkmcnt(0)" ::: "memory");
    __builtin_amdgcn_s_barrier();

    const __half* hrow = &hl[cur][s * 64];
    float acc[8] = {0.f, 0.f, 0.f, 0.f, 0.f, 0.f, 0.f, 0.f};

    // c = 0..5: U from registers
#pragma unroll
    for (int c = 0; c < 6; ++c) {
      const uint4 hq = *(const uint4*)(hrow + c * 8);
#pragma unroll
      for (int a = 0; a < 8; ++a) {
        const uint4 uv = R[a * 6 + c];
        acc[a] = dot2f16(uv.x, hq.x, acc[a]);
        acc[a] = dot2f16(uv.y, hq.y, acc[a]);
        acc[a] = dot2f16(uv.z, hq.z, acc[a]);
        acc[a] = dot2f16(uv.w, hq.w, acc[a]);
      }
    }
    // c = 6,7: U from LDS
#pragma unroll
    for (int c6 = 0; c6 < 2; ++c6) {
      const uint4 hq = *(const uint4*)(hrow + (6 + c6) * 8);
#pragma unroll
      for (int a = 0; a < 8; ++a) {
        const uint4 uv = *(const uint4*)(Ul + ((size_t)(a * 2 + c6) * 512 + j) * 8);
        acc[a] = dot2f16(uv.x, hq.x, acc[a]);
        acc[a] = dot2f16(uv.y, hq.y, acc[a]);
        acc[a] = dot2f16(uv.z, hq.z, acc[a]);
        acc[a] = dot2f16(uv.w, hq.w, acc[a]);
      }
    }

    // reduce over the 4 k-quarters within each lane quad
#pragma unroll
    for (int a = 0; a < 8; ++a) {
      acc[a] += __shfl_xor(acc[a], 1);
      acc[a] += __shfl_xor(acc[a], 2);
    }

    // lane s=0 handles n=2u (accums 0..3), s=1 handles n=2u+1 (accums 4..7)
    const int hiSel = s & 1;
    const float af = hiSel ? acc[4] : acc[0];
    const float ai = hiSel ? acc[5] : acc[1];
    const float ao = hiSel ? acc[6] : acc[2];
    const float ac = hiSel ? acc[7] : acc[3];

    const __half2 x01 = __builtin_bit_cast(__half2, xgc.x);
    const __half2 x23 = __builtin_bit_cast(__half2, xgc.y);
    const float gf = fsigmoid(af + __half2float(x01.x));
    const float gi = fsigmoid(ai + __half2float(x01.y));
    const float go = fsigmoid(ao + __half2float(x23.x));
    const float cd = ftanh_(ac + __half2float(x23.y));
    cst = gf * cst + gi * cd;
    const float hv = go * ftanh_(cst);

    if (s < 2) {
      hl[nxt][nsel] = __float2half(hv);
      ob[(size_t)t * HH + nsel] = hv;
    }
    xgc = xgn;
    cur = nxt;
  }
}

// ---------------------------------------------------------------------------
// Fallback path (round-1 kernel, needs only 768 KB ws)
// ---------------------------------------------------------------------------

__global__ void repack_kernel(const float* __restrict__ wf, const float* __restrict__ wi,
                              const float* __restrict__ wo, const float* __restrict__ wc,
                              const float* __restrict__ uf, const float* __restrict__ ui,
                              const float* __restrict__ uo, const float* __restrict__ uc,
                              __half* __restrict__ Vt) {
  int idx = blockIdx.x * 256 + threadIdx.x;
  int gq = idx >> 13;
  int g = gq / 12;
  int q = gq - g * 12;
  int rem = idx & 8191;
  int jj = rem >> 3;
  int r = rem & 7;
  int n = jj >> 2;
  int s = jj & 3;
  int k = s * 96 + q * 8 + r;
  const float* Wg[4] = {wf, wi, wo, wc};
  const float* Ug[4] = {uf, ui, uo, uc};
  float v = (k < DD) ? Wg[g][k * HH + n] : Ug[g][(k - DD) * HH + n];
  Vt[idx] = __float2half(v);
}

__global__ __launch_bounds__(1024, 4) void lstm_kernel(
    const float* __restrict__ x, const __half* __restrict__ Vt,
    const float* __restrict__ bf, const float* __restrict__ bi,
    const float* __restrict__ bo, const float* __restrict__ bc,
    float* __restrict__ out) {
  __shared__ __align__(16) __half hx[2][384];
  const int j = threadIdx.x;
  const int b = blockIdx.x;
  const int n = j >> 2;
  const int s = j & 3;
  const float* xb = x + (size_t)b * TT * DD;
  float* ob = out + (size_t)b * TT * HH;
  const float bias_f = bf[n], bias_i = bi[n], bias_o = bo[n], bias_c = bc[n];

  if (j < HH) hx[0][DD + j] = __float2half(0.f);
  if (j < 32) {
    float4 xa = ((const float4*)xb)[j];
    __half2* dst = (__half2*)hx[0];
    __half2 p0q; p0q.x = __float2half(xa.x); p0q.y = __float2half(xa.y);
    __half2 p1q; p1q.x = __float2half(xa.z); p1q.y = __float2half(xa.w);
    dst[2 * j] = p0q; dst[2 * j + 1] = p1q;
  }
  float c = 0.f;
  const uint4* vbase = (const uint4*)Vt + j;
  int cur = 0;
  for (int t = 0; t < TT; ++t) {
    const int nxt = cur ^ 1;
    __syncthreads();
    if (j < 32 && t + 1 < TT) {
      float4 xa = ((const float4*)(xb + (size_t)(t + 1) * DD))[j];
      __half2* dst = (__half2*)hx[nxt];
      __half2 p0q; p0q.x = __float2half(xa.x); p0q.y = __float2half(xa.y);
      __half2 p1q; p1q.x = __float2half(xa.z); p1q.y = __float2half(xa.w);
      dst[2 * j] = p0q; dst[2 * j + 1] = p1q;
    }
    float af = 0.f, ai = 0.f, ao = 0.f, ac = 0.f;
    const uint4* hp = (const uint4*)(&hx[cur][s * 96]);
#pragma unroll 4
    for (int q = 0; q < 12; ++q) {
      uint4 hq = hp[q];
      uint4 v0 = vbase[(0 * 12 + q) * 1024];
      uint4 v1 = vbase[(1 * 12 + q) * 1024];
      uint4 v2 = vbase[(2 * 12 + q) * 1024];
      uint4 v3 = vbase[(3 * 12 + q) * 1024];
      af = dot2f16(v0.x, hq.x, af); af = dot2f16(v0.y, hq.y, af);
      af = dot2f16(v0.z, hq.z, af); af = dot2f16(v0.w, hq.w, af);
      ai = dot2f16(v1.x, hq.x, ai); ai = dot2f16(v1.y, hq.y, ai);
      ai = dot2f16(v1.z, hq.z, ai); ai = dot2f16(v1.w, hq.w, ai);
      ao = dot2f16(v2.x, hq.x, ao); ao = dot2f16(v2.y, hq.y, ao);
      ao = dot2f16(v2.z, hq.z, ao); ao = dot2f16(v2.w, hq.w, ao);
      ac = dot2f16(v3.x, hq.x, ac); ac = dot2f16(v3.y, hq.y, ac);
      ac = dot2f16(v3.z, hq.z, ac); ac = dot2f16(v3.w, hq.w, ac);
    }
    af += __shfl_xor(af, 1); af += __shfl_xor(af, 2);
    ai += __shfl_xor(ai, 1); ai += __shfl_xor(ai, 2);
    ao += __shfl_xor(ao, 1); ao += __shfl_xor(ao, 2);
    ac += __shfl_xor(ac, 1); ac += __shfl_xor(ac, 2);
    float fg = fsigmoid(af + bias_f);
    float ig = fsigmoid(ai + bias_i);
    float og = fsigmoid(ao + bias_o);
    float cd = ftanh_(ac + bias_c);
    c = fg * c + ig * cd;
    float hv = og * ftanh_(c);
    if (s == 0) {
      hx[nxt][DD + n] = __float2half(hv);
      ob[(size_t)t * HH + n] = hv;
    }
    cur = nxt;
  }
}

// ---------------------------------------------------------------------------

extern "C" void kernel_launch(void* const* d_in, const int* in_sizes, int n_in,
                              void* d_out, int out_size, void* d_ws, size_t ws_size,
                              hipStream_t stream) {
  const float* x  = (const float*)d_in[0];
  const float* wf = (const float*)d_in[1];
  const float* wi = (const float*)d_in[2];
  const float* wo = (const float*)d_in[3];
  const float* wc = (const float*)d_in[4];
  const float* uf = (const float*)d_in[5];
  const float* ui = (const float*)d_in[6];
  const float* uo = (const float*)d_in[7];
  const float* uc = (const float*)d_in[8];
  const float* bf = (const float*)d_in[9];
  const float* bi = (const float*)d_in[10];
  const float* bo = (const float*)d_in[11];
  const float* bc = (const float*)d_in[12];

  const size_t UT_OFF = 0;                       // 524288 B
  const size_t WT_OFF = 524288;                  // 262144 B
  const size_t BS_OFF = 786432;                  // 4096 B
  const size_t XG_OFF = 790528;                  // 134217728 B
  const size_t NEED = XG_OFF + (size_t)BB * TT * 1024 * 2;

  if (ws_size >= NEED) {
    __half* Ut = (__half*)((char*)d_ws + UT_OFF);
    __half* Wt = (__half*)((char*)d_ws + WT_OFF);
    float*  bs = (float*)((char*)d_ws + BS_OFF);
    __half* xg = (__half*)((char*)d_ws + XG_OFF);

    repack_u3_kernel<<<1024, 256, 0, stream>>>(uf, ui, uo, uc, Ut);
    repack_w2_kernel<<<512, 256, 0, stream>>>(wf, wi, wo, wc, bf, bi, bo, bc, Wt, bs);
    xg_gemm_kernel<<<16384, 256, 0, stream>>>(x, Wt, bs, xg);
    lstm3_kernel<<<BB, 512, 0, stream>>>(Ut, xg, (float*)d_out);
  } else {
    __half* Vt = (__half*)d_ws;
    repack_kernel<<<1536, 256, 0, stream>>>(wf, wi, wo, wc, uf, ui, uo, uc, Vt);
    lstm_kernel<<<BB, 1024, 0, stream>>>(x, Vt, bf, bi, bo, bc, (float*)d_out);
  }
}